// Round 15
// baseline (1237.828 us; speedup 1.0000x reference)
//
#include <hip/hip_runtime.h>
#include <math.h>

typedef __bf16 bf16;
typedef __attribute__((ext_vector_type(8))) __bf16 bf16x8;
typedef __attribute__((ext_vector_type(4))) __bf16 bf16x4;
typedef __attribute__((ext_vector_type(4))) float f32x4;

// ---- problem constants ----
constexpr int B_ = 8;
constexpr int T_ = 128;
constexpr int D_ = 384;
constexpr int H_ = 6;
constexpr int DH_ = 64;
constexpr int L_ = 4;
constexpr int INTER_ = 1536;
constexpr int OUT_C = 80;
constexpr int TMEL_ = 1024;
constexpr int HD_ = 384;     // H*DH
constexpr int QKV_N = 1152;  // 3*HD

// Up to 8 split-K slice output pointers (passed by value as kernarg).
struct F8 {
  float* p[8];
};

// XCD-aware chunked swizzle (T1): bijective when nwg%8==0; identity otherwise.
__device__ __forceinline__ int xcd_swizzle(int bid, int nwg) {
  if (nwg & 7) return bid;
  return (bid & 7) * (nwg >> 3) + (bid >> 3);
}

// ===========================================================================
// Embedding + PE (PE indexed by BATCH per reference quirk): x = 2*emb + pe[b]
// Also computes the encoder key mask (fused).
// ===========================================================================
__global__ __launch_bounds__(256) void embed_kernel(
    const int* __restrict__ tokens, const float* __restrict__ emb,
    const int* __restrict__ tl, float* __restrict__ X, bf16* __restrict__ Xbf,
    float* __restrict__ maske) {
  int i = blockIdx.x * 256 + threadIdx.x;
  if (i >= B_ * T_ * D_) return;
  if (i < B_ * T_) {
    int bb = i / T_, tt = i % T_;
    maske[i] = (tt > tl[bb]) ? -INFINITY : 0.0f;
  }
  int d = i % D_;
  int bt = i / D_;
  int b = bt / T_, t = bt % T_;
  int tok = tokens[bt];
  int i2 = d & ~1;
  const float c = 9.210340371976184f / (float)D_;  // ln(10000)/D
  float freq = expf(-(float)i2 * c);
  float ang = (float)b * freq;
  float pe = (d & 1) ? cosf(ang) : sinf(ang);
  float v = 2.0f * emb[(size_t)tok * D_ + d] + pe;
  X[i] = v;
  Xbf[((size_t)b * (T_ + 2) + 1 + t) * D_ + d] = (bf16)v;
}

// ===========================================================================
// Weight transpose: src fp32 [K][N] -> dst bf16 [Ndst + rowOfs][K] row-major.
// ===========================================================================
__global__ __launch_bounds__(256) void transpose_w_kernel(
    const float* __restrict__ src, long srcLS, bf16* __restrict__ dst,
    long dstLS, int K, int N, int rowOfs) {
  src += (size_t)blockIdx.z * srcLS;
  dst += (size_t)blockIdx.z * dstLS;
  __shared__ float tile[32][33];
  const int tx = threadIdx.x & 31, ty = threadIdx.x >> 5;
  const int n0 = blockIdx.x * 32, k0 = blockIdx.y * 32;
#pragma unroll
  for (int j = 0; j < 4; ++j)
    tile[ty + j * 8][tx] =
        (n0 + tx < N) ? src[(size_t)(k0 + ty + j * 8) * N + n0 + tx] : 0.0f;
  __syncthreads();
#pragma unroll
  for (int j = 0; j < 4; ++j)
    dst[(size_t)(n0 + rowOfs + ty + j * 8) * K + k0 + tx] = (bf16)tile[tx][ty + j * 8];
}

// Zero padding rows of the three padded bf16 activation buffers in one launch.
__global__ void zero_pads3_kernel(bf16* a, bf16* c, bf16* m, int Tp) {
  int b = blockIdx.x >> 1, side = blockIdx.x & 1;
  size_t row = (size_t)b * (Tp + 2) + (side ? (Tp + 1) : 0);
  bf16* buf = (blockIdx.y == 0) ? a : (blockIdx.y == 1) ? c : m;
  int C = (blockIdx.y == 2) ? INTER_ : D_;
  for (int cc = threadIdx.x; cc < C; cc += 256) buf[row * C + cc] = (bf16)0.0f;
}

// ===========================================================================
// 128x128 GEMM, BK=32, 4-buffer LDS pipeline, 3-tile-ahead prefetch, ONE
// barrier per K-step: {gate vmcnt(8); barrier; issue stage(t+3); compute}.
// Barrier-at-iter-t guarantees all waves finished iter t-1 compute before
// buf[(t+3)&3] (== buf[(t-1)&3]) is overwritten; per-wave vmcnt gate +
// barrier guarantees tile-t LDS writes landed. Never drains mid-loop (T4).
// Split-K slices via sp.p[z] (bias on z==0; relu only used when nz==1).
// nact: gap-tile skip (tiles [0,nact) + last tile kept).
// VTout: fused V-transpose; haloC: fused conv halo (rows act & 895).
// ===========================================================================
template <int TP>
__global__ __launch_bounds__(256) void mfma_gemm_kernel(
    const bf16* __restrict__ A, int lda, int aofs,
    const bf16* __restrict__ WT, int ldw, int kslice,
    const float* __restrict__ bias, int relu, F8 sp,
    bf16* __restrict__ Cbf, int ldc, int transC,
    const int* __restrict__ nact, bf16* __restrict__ VTout, int haloC) {
  __shared__ bf16 As[4][128 * 32];
  __shared__ bf16 Bs[4][128 * 32];
  const int tid = threadIdx.x;
  const int lane = tid & 63;
  const int wave = tid >> 6;
  const int wr = wave >> 1, wc = wave & 1;

  const int nT = gridDim.x, mT = gridDim.y;
  const int nwg = nT * mT * gridDim.z;
  int bid = blockIdx.x + nT * (blockIdx.y + mT * blockIdx.z);
  int wid = xcd_swizzle(bid, nwg);
  const int bx = wid % nT;
  int tmp = wid / nT;
  const int by = tmp % mT;
  const int z = tmp / mT;

  const int rowBase = by * 128;
  const int colBase = bx * 128;
  const int k0beg = z * kslice;
  const int nt = kslice / 32;
  const int bb = rowBase / TP;
  constexpr int LASTT = TP / 128 - 1;
  if (nact) {
    int tloc = (rowBase - bb * TP) >> 7;
    if (tloc >= nact[bb] && tloc != LASTT) return;  // gap-tile skip
  }
  const long pr0 = (long)bb * (TP + 2) + 1 + (rowBase - bb * TP);
  const long abase = pr0 * (long)lda - aofs;

  const int srow = tid >> 2, scb = tid & 3;

  auto stage = [&](int t, int buf) {  // 4 VMEM instructions per thread
    const int k0 = k0beg + t * 32;
#pragma unroll
    for (int e = 0; e < 2; ++e) {
      int idx = e * 256 + tid;
      int lrow = srow + e * 64;
      const bf16* gp = A + abase + (long)lrow * lda + k0 + ((scb ^ ((lrow >> 1) & 3)) << 3);
      __builtin_amdgcn_global_load_lds(
          (const __attribute__((address_space(1))) unsigned int*)gp,
          (__attribute__((address_space(3))) unsigned int*)(As[buf] + idx * 8), 16, 0, 0);
    }
#pragma unroll
    for (int e = 0; e < 2; ++e) {
      int idx = e * 256 + tid;
      int lrow = srow + e * 64;
      const bf16* gp = WT + (long)(colBase + lrow) * ldw + k0 + ((scb ^ ((lrow >> 1) & 3)) << 3);
      __builtin_amdgcn_global_load_lds(
          (const __attribute__((address_space(1))) unsigned int*)gp,
          (__attribute__((address_space(3))) unsigned int*)(Bs[buf] + idx * 8), 16, 0, 0);
    }
  };

  f32x4 acc[4][4] = {};
  const int g = lane >> 4, l15 = lane & 15;

  stage(0, 0);
  if (nt > 1) stage(1, 1);
  if (nt > 2) stage(2, 2);
  for (int t = 0; t < nt; ++t) {
    // gate: retire tile t's 4 loads; keep (up to) 2 stages in flight
    int ahead = nt - 1 - t;
    if (ahead >= 2)
      asm volatile("s_waitcnt vmcnt(8)" ::: "memory");
    else if (ahead == 1)
      asm volatile("s_waitcnt vmcnt(4)" ::: "memory");
    else
      asm volatile("s_waitcnt vmcnt(0)" ::: "memory");
    __builtin_amdgcn_s_barrier();  // all waves: tile-t landed AND t-1 compute done
    asm volatile("" ::: "memory");
    if (t + 3 < nt) stage(t + 3, (t + 3) & 3);

    const bf16* Asb = As[t & 3];
    const bf16* Bsb = Bs[t & 3];
    bf16x8 af[4], bw[4];
#pragma unroll
    for (int m = 0; m < 4; ++m) {
      int row = wr * 64 + m * 16 + l15;
      int cb = g ^ ((row >> 1) & 3);
      af[m] = *(const bf16x8*)(Asb + row * 32 + cb * 8);
    }
#pragma unroll
    for (int n = 0; n < 4; ++n) {
      int row = wc * 64 + n * 16 + l15;
      int cb = g ^ ((row >> 1) & 3);
      bw[n] = *(const bf16x8*)(Bsb + row * 32 + cb * 8);
    }
#pragma unroll
    for (int m = 0; m < 4; ++m)
#pragma unroll
      for (int n = 0; n < 4; ++n)
        acc[m][n] = __builtin_amdgcn_mfma_f32_16x16x32_bf16(af[m], bw[n], acc[m][n], 0, 0, 0);
    asm volatile("" ::: "memory");
  }

  float* Cfz = sp.p[z];
  const float* biasz = z ? nullptr : bias;
  const int qr = (lane >> 4) * 4;
  const int qc = lane & 15;
  const int actR = (haloC && nact) ? nact[bb] * 128 : -1;
#pragma unroll
  for (int m = 0; m < 4; ++m) {
    int lrow = wr * 64 + m * 16 + qr;
    int tl0 = rowBase - bb * TP + lrow;
#pragma unroll
    for (int n = 0; n < 4; ++n) {
      int gcol = colBase + wc * 64 + n * 16 + qc;
      float bv = (biasz && (!transC || gcol < OUT_C)) ? biasz[gcol] : 0.0f;
      float vq[4];
#pragma unroll
      for (int q = 0; q < 4; ++q) {
        float v = acc[m][n][q] + bv;
        if (relu) v = fmaxf(v, 0.0f);
        vq[q] = v;
      }
      if (transC) {
        if (gcol < OUT_C)
#pragma unroll
          for (int q = 0; q < 4; ++q)
            Cfz[((long)bb * OUT_C + gcol) * TMEL_ + tl0 + q] = vq[q];
      } else {
        if (Cfz)
#pragma unroll
          for (int q = 0; q < 4; ++q)
            Cfz[(long)(rowBase + lrow + q) * ldc + gcol] = vq[q];
        if (Cbf) {
#pragma unroll
          for (int q = 0; q < 4; ++q)
            Cbf[(pr0 + lrow + q) * ldc + gcol] = (bf16)vq[q];
          if (actR >= 0 && actR < 896) {
#pragma unroll
            for (int q = 0; q < 4; ++q)
              if (tl0 + q == actR - 1) {
                long pb = (long)bb * (TP + 2) + 1;
                bf16 hv = (bf16)vq[q];
                Cbf[(pb + actR) * (long)ldc + gcol] = hv;
                Cbf[(pb + 895) * (long)ldc + gcol] = hv;
              }
          }
        }
        if (VTout && gcol >= 768) {
          int hh = (gcol - 768) >> 6, dh = (gcol - 768) & 63;
          bf16x4 pk;
#pragma unroll
          for (int q = 0; q < 4; ++q) pk[q] = (bf16)vq[q];
          *(bf16x4*)(VTout + (((size_t)(bb * H_ + hh) * DH_ + dh) * TP + tl0)) = pk;
        }
      }
    }
  }
}

// ===========================================================================
// MFMA flash attention: key-tile skip + q-tile gap skip (last tile kept).
// ===========================================================================
__global__ __launch_bounds__(256) void attn4_kernel(
    const bf16* __restrict__ QKV, const bf16* __restrict__ VT,
    const float* __restrict__ maskadd, const int* __restrict__ lens,
    const int* __restrict__ nactp, bf16* __restrict__ Obf, int T) {
  const int nQT = gridDim.x;
  const int nwg = nQT * H_ * B_;
  int bid = blockIdx.x + nQT * (blockIdx.y + H_ * blockIdx.z);
  int wid = xcd_swizzle(bid, nwg);
  const int qt = wid % nQT;
  int tmp = wid / nQT;
  const int h = tmp % H_;
  const int b = tmp / H_;
  if (nactp) {
    int tloc = qt >> 1;  // 128-row tile index
    if (tloc >= nactp[b] && tloc != ((T >> 7) - 1)) return;
  }

  const int tid = threadIdx.x;
  const int lane = tid & 63;
  const int wave = tid >> 6;
  const int l15 = lane & 15, g = lane >> 4;

  __shared__ bf16 Ks[64 * 64];
  __shared__ bf16 Vts[64 * 64];
  __shared__ bf16 Ps[4][16 * 64];
  __shared__ float mask_s[TMEL_];

  const int q0 = qt * 64;
  const size_t brow0 = (size_t)b * (T + 2) + 1;

  for (int i = tid; i < T; i += 256) mask_s[i] = maskadd[(size_t)b * T + i];

  const size_t qrow = brow0 + q0 + wave * 16 + l15;
  bf16x8 qf0 = *(const bf16x8*)(QKV + qrow * QKV_N + h * DH_ + g * 8);
  bf16x8 qf1 = *(const bf16x8*)(QKV + qrow * QKV_N + h * DH_ + g * 8 + 32);

  float mreg[4], lreg[4];
#pragma unroll
  for (int r = 0; r < 4; ++r) { mreg[r] = -INFINITY; lreg[r] = 0.0f; }
  f32x4 oacc[4] = {};
  bf16* Psb = Ps[wave];

  const int nt = min(T >> 6, (lens[b] + 64) >> 6);
  for (int t = 0; t < nt; ++t) {
    const int k0 = t * 64;
#pragma unroll
    for (int it = 0; it < 2; ++it) {
      int c = it * 256 + tid;
      int r = c >> 3, d0 = c & 7;
      bf16x8 kv = *(const bf16x8*)(QKV + (brow0 + k0 + r) * QKV_N + 384 + h * DH_ + d0 * 8);
      *(bf16x8*)(Ks + r * 64 + ((d0 ^ (r & 7)) << 3)) = kv;
      bf16x8 vv = *(const bf16x8*)(VT + ((size_t)(b * H_ + h) * DH_ + r) * T + k0 + d0 * 8);
      *(bf16x8*)(Vts + r * 64 + ((d0 ^ (r & 7)) << 3)) = vv;
    }
    __syncthreads();

    f32x4 sacc[4] = {};
#pragma unroll
    for (int ks = 0; ks < 2; ++ks) {
#pragma unroll
      for (int n = 0; n < 4; ++n) {
        int key = n * 16 + l15;
        bf16x8 bf = *(const bf16x8*)(Ks + key * 64 + (((g + ks * 4) ^ (key & 7)) << 3));
        sacc[n] = __builtin_amdgcn_mfma_f32_16x16x32_bf16(ks ? qf1 : qf0, bf, sacc[n], 0, 0, 0);
      }
    }

    float s[4][4];
    float tm[4] = {-INFINITY, -INFINITY, -INFINITY, -INFINITY};
#pragma unroll
    for (int n = 0; n < 4; ++n) {
      float mv = mask_s[k0 + n * 16 + l15];
#pragma unroll
      for (int r = 0; r < 4; ++r) {
        float v = sacc[n][r] * 0.125f + mv;
        s[n][r] = v;
        tm[r] = fmaxf(tm[r], v);
      }
    }
#pragma unroll
    for (int msk = 1; msk < 16; msk <<= 1)
#pragma unroll
      for (int r = 0; r < 4; ++r) tm[r] = fmaxf(tm[r], __shfl_xor(tm[r], msk));

    float sc[4];
#pragma unroll
    for (int r = 0; r < 4; ++r) {
      float mn = fmaxf(mreg[r], tm[r]);
      sc[r] = __expf(mreg[r] - mn);
      mreg[r] = mn;
    }
    float psum[4] = {0.0f, 0.0f, 0.0f, 0.0f};
#pragma unroll
    for (int n = 0; n < 4; ++n) {
      int key = n * 16 + l15;
      int kblk = key >> 3, kin = key & 7;
#pragma unroll
      for (int r = 0; r < 4; ++r) {
        float p = __expf(s[n][r] - mreg[r]);
        psum[r] += p;
        int q = g * 4 + r;
        Psb[q * 64 + ((kblk ^ (q & 7)) << 3) + kin] = (bf16)p;
      }
    }
#pragma unroll
    for (int msk = 1; msk < 16; msk <<= 1)
#pragma unroll
      for (int r = 0; r < 4; ++r) psum[r] += __shfl_xor(psum[r], msk);
#pragma unroll
    for (int r = 0; r < 4; ++r) lreg[r] = lreg[r] * sc[r] + psum[r];
#pragma unroll
    for (int n = 0; n < 4; ++n)
#pragma unroll
      for (int r = 0; r < 4; ++r) oacc[n][r] *= sc[r];

#pragma unroll
    for (int ks = 0; ks < 2; ++ks) {
      bf16x8 af = *(const bf16x8*)(Psb + l15 * 64 + (((g + ks * 4) ^ (l15 & 7)) << 3));
#pragma unroll
      for (int n = 0; n < 4; ++n) {
        int dh = n * 16 + l15;
        bf16x8 bv = *(const bf16x8*)(Vts + dh * 64 + (((g + ks * 4) ^ (dh & 7)) << 3));
        oacc[n] = __builtin_amdgcn_mfma_f32_16x16x32_bf16(af, bv, oacc[n], 0, 0, 0);
      }
    }
    __syncthreads();
  }

  float inv[4];
#pragma unroll
  for (int r = 0; r < 4; ++r) inv[r] = 1.0f / lreg[r];
  const size_t orow = brow0 + q0 + wave * 16 + g * 4;
#pragma unroll
  for (int n = 0; n < 4; ++n)
#pragma unroll
    for (int r = 0; r < 4; ++r)
      Obf[(orow + r) * D_ + h * DH_ + n * 16 + l15] = (bf16)(oacc[n][r] * inv[r]);
}

// ===========================================================================
// Y = LN(opt-relu(X + sum_{i<nsl} sp.p[i])) * g + b. float4-vectorized.
// X nullable. Gap-tile skip (last tile kept); halo rows act & 895.
// ===========================================================================
__global__ __launch_bounds__(128) void add_ln_kernel(
    const float* __restrict__ X, F8 sp, int nsl,
    const float* __restrict__ g, const float* __restrict__ bb,
    float* __restrict__ Yf, bf16* __restrict__ Ybf, int tshift, int relu,
    const int* __restrict__ nactp, int halo) {
  const int row = blockIdx.x;
  const int b = row >> tshift, t = row & ((1 << tshift) - 1);
  if (nactp) {
    int tloc = t >> 7;
    if (tloc >= nactp[b] && tloc != (((1 << tshift) >> 7) - 1)) return;
  }
  const int tid = threadIdx.x;
  const bool lact = tid < 96;
  __shared__ float red[128];
  float4 v = make_float4(0.f, 0.f, 0.f, 0.f);
  if (lact) {
    if (X) v = ((const float4*)(X + (size_t)row * D_))[tid];
    for (int s = 0; s < nsl; ++s) {
      float4 h = ((const float4*)(sp.p[s] + (size_t)row * D_))[tid];
      v.x += h.x; v.y += h.y; v.z += h.z; v.w += h.w;
    }
    if (relu) {
      v.x = fmaxf(v.x, 0.f); v.y = fmaxf(v.y, 0.f);
      v.z = fmaxf(v.z, 0.f); v.w = fmaxf(v.w, 0.f);
    }
  }
  red[tid] = v.x + v.y + v.z + v.w;
  __syncthreads();
  for (int off = 64; off > 0; off >>= 1) {
    if (tid < off) red[tid] += red[tid + off];
    __syncthreads();
  }
  float mean = red[0] / (float)D_;
  __syncthreads();
  float dx = v.x - mean, dy = v.y - mean, dz = v.z - mean, dw = v.w - mean;
  red[tid] = lact ? (dx * dx + dy * dy + dz * dz + dw * dw) : 0.0f;
  __syncthreads();
  for (int off = 64; off > 0; off >>= 1) {
    if (tid < off) red[tid] += red[tid + off];
    __syncthreads();
  }
  float invstd = rsqrtf(red[0] / (float)D_ + 1e-5f);
  __syncthreads();
  if (!lact) return;
  float4 gv = ((const float4*)g)[tid];
  float4 bv = ((const float4*)bb)[tid];
  float4 y;
  y.x = dx * invstd * gv.x + bv.x;
  y.y = dy * invstd * gv.y + bv.y;
  y.z = dz * invstd * gv.z + bv.z;
  y.w = dw * invstd * gv.w + bv.w;
  ((float4*)(Yf + (size_t)row * D_))[tid] = y;
  if (Ybf) {
    const size_t pbase = (size_t)b * ((1 << tshift) + 2) + 1;
    bf16x4 p;
    p[0] = (bf16)y.x; p[1] = (bf16)y.y; p[2] = (bf16)y.z; p[3] = (bf16)y.w;
    *(bf16x4*)(Ybf + (pbase + t) * D_ + tid * 4) = p;
    if (halo && nactp) {
      int act = nactp[b] * 128;
      if (act < 896 && t == act - 1) {
        *(bf16x4*)(Ybf + (pbase + act) * D_ + tid * 4) = p;
        *(bf16x4*)(Ybf + (pbase + 895) * D_ + tid * 4) = p;
      }
    }
  }
}

__global__ __launch_bounds__(64) void dp_linear_kernel(
    const float* __restrict__ Hh, const float* __restrict__ w,
    const float* __restrict__ b0, float* __restrict__ lp) {
  const int row = blockIdx.x;
  const int tid = threadIdx.x;
  float s = 0.0f;
  for (int d = tid; d < D_; d += 64) s += Hh[(size_t)row * D_ + d] * w[d];
#pragma unroll
  for (int off = 32; off > 0; off >>= 1) s += __shfl_down(s, off);
  if (tid == 0) lp[row] = s + b0[0];
}

// ---------------------------------------------------------------------------
// Length regulator (fused scan + build; cumsum in LDS).
// ---------------------------------------------------------------------------
__global__ __launch_bounds__(256) void lr_prep_kernel(
    const int* __restrict__ dur, int* __restrict__ mel, int* __restrict__ nact,
    int* __restrict__ idx, float* __restrict__ maskd) {
  int b = blockIdx.x;
  __shared__ int cs_s[T_];
  __shared__ int smel;
  if (threadIdx.x == 0) {
    int s = 0;
    for (int t = 0; t < T_; ++t) {
      s += dur[b * T_ + t];
      cs_s[t] = s;
    }
    smel = s;
    mel[b] = s;
    nact[b] = (min(TMEL_, s + 9) + 127) >> 7;
  }
  __syncthreads();
  int mlen = smel;
  for (int m = threadIdx.x; m < TMEL_; m += 256) {
    int t = -1;
    if (m < mlen) {
      int lo = 0, hi = T_ - 1;
      while (lo < hi) {
        int mid = (lo + hi) >> 1;
        if (cs_s[mid] > m) hi = mid; else lo = mid + 1;
      }
      t = lo;
    }
    idx[b * TMEL_ + m] = t;
    maskd[b * TMEL_ + m] = (m > mlen) ? -INFINITY : 0.0f;
  }
}

__global__ __launch_bounds__(128) void lr_gather_kernel(
    const float* __restrict__ XE, const int* __restrict__ idx,
    float* __restrict__ XD, bf16* __restrict__ XDbf) {
  int row = blockIdx.x;
  int b = row / TMEL_, m = row % TMEL_;
  int t = idx[row];
  size_t prow = ((size_t)b * (TMEL_ + 2) + 1 + m) * D_;
  for (int d = threadIdx.x; d < D_; d += 128) {
    float v = (t >= 0) ? XE[((size_t)(b * T_ + t)) * D_ + d] : 0.0f;
    XD[(size_t)row * D_ + d] = v;
    XDbf[prow + d] = (bf16)v;
  }
}

// Broadcast gap mel columns [act*128, 896) from class column act*128-1.
__global__ void bcast_out_kernel(float* __restrict__ out,
                                 const int* __restrict__ nact) {
  int b = blockIdx.x / OUT_C, o = blockIdx.x % OUT_C;
  int act = nact[b] * 128;
  if (act >= 896) return;
  float* row = out + ((size_t)b * OUT_C + o) * TMEL_;
  float v = row[act - 1];
  for (int m = act + threadIdx.x; m < 896; m += 256) row[m] = v;
}

// ===========================================================================
// Host
// ===========================================================================
extern "C" void kernel_launch(void* const* d_in, const int* in_sizes, int n_in,
                              void* d_out, int out_size, void* d_ws, size_t ws_size,
                              hipStream_t stream) {
  const int* tokens = (const int*)d_in[0];
  const int* token_lengths = (const int*)d_in[1];
  const int* durations = (const int*)d_in[2];
  const float* emb = (const float*)d_in[3];
  const float* encw[12];
  const float* decw[12];
  for (int i = 0; i < 12; ++i) encw[i] = (const float*)d_in[4 + i];
  for (int i = 0; i < 12; ++i) decw[i] = (const float*)d_in[16 + i];
  const float* dp_c1w = (const float*)d_in[28];
  const float* dp_c1b = (const float*)d_in[29];
  const float* dp_ln1g = (const float*)d_in[30];
  const float* dp_ln1b = (const float*)d_in[31];
  const float* dp_c2w = (const float*)d_in[32];
  const float* dp_c2b = (const float*)d_in[33];
  const float* dp_ln2g = (const float*)d_in[34];
  const float* dp_ln2b = (const float*)d_in[35];
  const float* dp_w = (const float*)d_in[36];
  const float* dp_b = (const float*)d_in[37];
  const float* out_w = (const float*)d_in[38];
  const float* out_b = (const float*)d_in[39];

  float* out0 = (float*)d_out;                        // [B, OUT, TMEL]
  float* out_lp = out0 + (size_t)B_ * OUT_C * TMEL_;  // [B, T]

  // ---- workspace ----
  char* wsB = (char*)d_ws;
  size_t off = 0;
  auto alloc = [&](size_t bytes) {
    void* p = wsB + off;
    off = (off + bytes + 255) & ~(size_t)255;
    return p;
  };
  float* XE = (float*)alloc((size_t)B_ * T_ * D_ * 4);
  float* XD = (float*)alloc((size_t)B_ * TMEL_ * D_ * 4);
  float* YT = (float*)alloc((size_t)B_ * TMEL_ * D_ * 4);
  bf16* XEbf = (bf16*)alloc((size_t)B_ * (T_ + 2) * D_ * 2);
  bf16* XDbf = (bf16*)alloc((size_t)B_ * (TMEL_ + 2) * D_ * 2);
  bf16* YTbf = (bf16*)alloc((size_t)B_ * (TMEL_ + 2) * D_ * 2);
  bf16* MIDbf = (bf16*)alloc((size_t)B_ * (TMEL_ + 2) * INTER_ * 2);
  bf16* QKVbf = (bf16*)alloc((size_t)B_ * (TMEL_ + 2) * QKV_N * 2);
  bf16* OBbf = (bf16*)alloc((size_t)B_ * (TMEL_ + 2) * D_ * 2);   // 6.30 MB
  bf16* VTb = (bf16*)alloc((size_t)B_ * H_ * DH_ * TMEL_ * 2);    // 6.29 MB, adjacent
  float* OF = (float*)QKVbf;  // fp32 slice 0 (aliases QKVbf; disjoint lifetime)
  float* PT2 = (float*)OBbf;  // conv2 slice 1: OBbf+VTb contiguous span (both dead)
  float* YTal = (float*)YT;   // WO slice 1: YT dead there; add_ln reads first
  float* XDal = (float*)XD;   // dec conv2 slice 2: XD dead during conv2
  float* EARENA = (float*)((char*)MIDbf + (8u << 20));  // enc conv2 slices (MIDbf tail)
  float* DARENA = (float*)MIDbf;                        // DP slices (MIDbf dead)
  const size_t ESS = (size_t)B_ * T_ * D_;  // per-slice elems

  bf16* QKVT = (bf16*)alloc((size_t)L_ * QKV_N * D_ * 2);
  bf16* WOT = (bf16*)alloc((size_t)L_ * D_ * D_ * 2);
  bf16* C1T = (bf16*)alloc((size_t)L_ * INTER_ * (3 * D_) * 2);
  bf16* C2T = (bf16*)alloc((size_t)L_ * D_ * (3 * INTER_) * 2);
  bf16* DP1T = (bf16*)alloc((size_t)D_ * (3 * D_) * 2);
  bf16* DP2T = (bf16*)alloc((size_t)D_ * (3 * D_) * 2);
  bf16* OUTT = (bf16*)alloc((size_t)128 * D_ * 2);
  float* MASKE = (float*)alloc(B_ * T_ * 4);
  float* MASKD = (float*)alloc(B_ * TMEL_ * 4);
  int* MEL = (int*)alloc(B_ * 4);
  int* NACT = (int*)alloc(B_ * 4);
  int* IDX = (int*)alloc(B_ * TMEL_ * 4);

  auto tw = [&](const float* s, long sls, bf16* d, long dls, int K, int N,
                int Ndst, int ro, int Lz) {
    transpose_w_kernel<<<dim3(Ndst / 32, K / 32, Lz), 256, 0, stream>>>(s, sls, d, dls, K, N, ro);
  };
  auto gemm = [&](int TP, int nT, int mT, int nz, const bf16* A, int lda, int aofs,
                  const bf16* WTp, int ldw, int kslice, const float* bias, int relu,
                  F8 sp, bf16* Cbf, int ldc, int transC,
                  const int* nact, bf16* VTout, int haloC) {
    dim3 gd(nT, mT, nz);
    if (TP == 128)
      mfma_gemm_kernel<128><<<gd, 256, 0, stream>>>(A, lda, aofs, WTp, ldw, kslice,
                                                    bias, relu, sp, Cbf, ldc, transC,
                                                    nact, VTout, haloC);
    else
      mfma_gemm_kernel<1024><<<gd, 256, 0, stream>>>(A, lda, aofs, WTp, ldw, kslice,
                                                     bias, relu, sp, Cbf, ldc, transC,
                                                     nact, VTout, haloC);
  };

  F8 spNull = {};
  auto run_layer = [&](int TP, const float* const* w, int i, float* Xf, bf16* Xbf,
                       const float* mask, const int* lens, const int* nact) {
    const int mT = B_ * TP / 128;
    const int tshift = (TP == 128) ? 7 : 10;
    // QKV GEMM with fused V-transpose
    gemm(TP, QKV_N / 128, mT, 1, Xbf, D_, 0, QKVT + (size_t)i * QKV_N * D_, D_, D_,
         nullptr, 0, spNull, QKVbf, QKV_N, 0, nact, VTb, 0);
    attn4_kernel<<<dim3(TP / 64, H_, B_), 256, 0, stream>>>(QKVbf, VTb, mask, lens, nact, OBbf, TP);
    // WO split-K=2
    F8 spWO = {};
    spWO.p[0] = OF; spWO.p[1] = YTal;
    gemm(TP, D_ / 128, mT, 2, OBbf, D_, 0, WOT + (size_t)i * D_ * D_, D_, D_ / 2,
         nullptr, 0, spWO, nullptr, D_, 0, nact, nullptr, 0);
    add_ln_kernel<<<B_ * TP, 128, 0, stream>>>(Xf, spWO, 2, w[4] + (size_t)i * D_,
                                               w[5] + (size_t)i * D_, YT, YTbf, tshift, 0,
                                               nact, 1);  // halo: YTbf rows act & 895
    // conv1 (nz=1, relu+bf16+halo in epilogue)
    gemm(TP, INTER_ / 128, mT, 1, YTbf, D_, D_, C1T + (size_t)i * INTER_ * 3 * D_, 3 * D_,
         3 * D_, w[7] + (size_t)i * INTER_, 1, spNull, MIDbf, INTER_, 0,
         nact, nullptr, 1);
    // conv2 split-K: encoder nz=8 (arena), decoder nz=3 (OF, PT2, XD)
    F8 spC2 = {};
    int nzC2;
    if (TP == 128) {
      nzC2 = 8;
      for (int s = 0; s < 8; ++s) spC2.p[s] = EARENA + (size_t)s * ESS;
    } else {
      nzC2 = 3;
      spC2.p[0] = OF; spC2.p[1] = PT2; spC2.p[2] = XDal;
    }
    gemm(TP, D_ / 128, mT, nzC2, MIDbf, INTER_, INTER_, C2T + (size_t)i * D_ * 3 * INTER_,
         3 * INTER_, 3 * INTER_ / nzC2, w[9] + (size_t)i * D_, 0, spC2, nullptr, D_, 0,
         nact, nullptr, 0);
    add_ln_kernel<<<B_ * TP, 128, 0, stream>>>(YT, spC2, nzC2, w[10] + (size_t)i * D_,
                                               w[11] + (size_t)i * D_, Xf, Xbf, tshift, 0,
                                               nact, 0);
  };

  // 1) embed + enc mask (fused) + pad zeroing
  embed_kernel<<<(B_ * T_ * D_ + 255) / 256, 256, 0, stream>>>(tokens, emb, token_lengths,
                                                               XE, XEbf, MASKE);
  zero_pads3_kernel<<<dim3(B_ * 2, 3), 256, 0, stream>>>(XEbf, YTbf, MIDbf, T_);

  // 2) encoder weights (batched) + stack
  tw(encw[0], (long)D_ * HD_, QKVT, (long)QKV_N * D_, D_, HD_, HD_, 0, L_);
  tw(encw[1], (long)D_ * HD_, QKVT, (long)QKV_N * D_, D_, HD_, HD_, 384, L_);
  tw(encw[2], (long)D_ * HD_, QKVT, (long)QKV_N * D_, D_, HD_, HD_, 768, L_);
  tw(encw[3], (long)HD_ * D_, WOT, (long)D_ * D_, HD_, D_, D_, 0, L_);
  tw(encw[6], (long)3 * D_ * INTER_, C1T, (long)INTER_ * 3 * D_, 3 * D_, INTER_, INTER_, 0, L_);
  tw(encw[8], (long)3 * INTER_ * D_, C2T, (long)D_ * 3 * INTER_, 3 * INTER_, D_, D_, 0, L_);
  for (int i = 0; i < L_; ++i)
    run_layer(T_, encw, i, XE, XEbf, MASKE, token_lengths, nullptr);

  // 3) duration predictor (split-K=4 via DP arena; relu in add_ln)
  tw(dp_c1w, 0, DP1T, 0, 3 * D_, D_, D_, 0, 1);
  tw(dp_c2w, 0, DP2T, 0, 3 * D_, D_, D_, 0, 1);
  F8 spDP = {};
  for (int s = 0; s < 4; ++s) spDP.p[s] = DARENA + (size_t)s * ESS;
  F8 spDPs = {};
  for (int s = 0; s < 3; ++s) spDPs.p[s] = DARENA + (size_t)(s + 1) * ESS;
  gemm(128, D_ / 128, B_, 4, XEbf, D_, D_, DP1T, 3 * D_, 3 * D_ / 4, dp_c1b, 0,
       spDP, nullptr, D_, 0, nullptr, nullptr, 0);
  add_ln_kernel<<<B_ * T_, 128, 0, stream>>>(spDP.p[0], spDPs, 3, dp_ln1g, dp_ln1b,
                                             YT, YTbf, 7, 1, nullptr, 0);
  gemm(128, D_ / 128, B_, 4, YTbf, D_, D_, DP2T, 3 * D_, 3 * D_ / 4, dp_c2b, 0,
       spDP, nullptr, D_, 0, nullptr, nullptr, 0);
  add_ln_kernel<<<B_ * T_, 128, 0, stream>>>(spDP.p[0], spDPs, 3, dp_ln2g, dp_ln2b,
                                             YT, nullptr, 7, 1, nullptr, 0);
  dp_linear_kernel<<<B_ * T_, 64, 0, stream>>>(YT, dp_w, dp_b, out_lp);

  // 4) length regulator
  lr_prep_kernel<<<B_, 256, 0, stream>>>(durations, MEL, NACT, IDX, MASKD);
  zero_pads3_kernel<<<dim3(B_ * 2, 3), 256, 0, stream>>>(XDbf, YTbf, MIDbf, TMEL_);
  lr_gather_kernel<<<B_ * TMEL_, 128, 0, stream>>>(XE, IDX, XD, XDbf);

  // 5) decoder weights (batched) + stack (gap-tile skip via NACT)
  tw(decw[0], (long)D_ * HD_, QKVT, (long)QKV_N * D_, D_, HD_, HD_, 0, L_);
  tw(decw[1], (long)D_ * HD_, QKVT, (long)QKV_N * D_, D_, HD_, HD_, 384, L_);
  tw(decw[2], (long)D_ * HD_, QKVT, (long)QKV_N * D_, D_, HD_, HD_, 768, L_);
  tw(decw[3], (long)HD_ * D_, WOT, (long)D_ * D_, HD_, D_, D_, 0, L_);
  tw(decw[6], (long)3 * D_ * INTER_, C1T, (long)INTER_ * 3 * D_, 3 * D_, INTER_, INTER_, 0, L_);
  tw(decw[8], (long)3 * INTER_ * D_, C2T, (long)D_ * 3 * INTER_, 3 * INTER_, D_, D_, 0, L_);
  for (int i = 0; i < L_; ++i)
    run_layer(TMEL_, decw, i, XD, XDbf, MASKD, MEL, NACT);

  // 6) final projection (gap skip, last tile computed) + gap column broadcast
  tw(out_w, 0, OUTT, 0, D_, OUT_C, 128, 0, 1);
  F8 spOut = {};
  spOut.p[0] = out0;
  gemm(1024, 1, B_ * TMEL_ / 128, 1, XDbf, D_, 0, OUTT, D_, D_, out_b, 0,
       spOut, nullptr, 0, 1, NACT, nullptr, 0);
  bcast_out_kernel<<<B_ * OUT_C, 256, 0, stream>>>(out0, NACT);
}

// Round 17
// 1138.949 us; speedup vs baseline: 1.0868x; 1.0868x over previous
//
#include <hip/hip_runtime.h>
#include <math.h>

typedef __bf16 bf16;
typedef __attribute__((ext_vector_type(8))) __bf16 bf16x8;
typedef __attribute__((ext_vector_type(4))) __bf16 bf16x4;
typedef __attribute__((ext_vector_type(4))) float f32x4;

// ---- problem constants ----
constexpr int B_ = 8;
constexpr int T_ = 128;
constexpr int D_ = 384;
constexpr int H_ = 6;
constexpr int DH_ = 64;
constexpr int L_ = 4;
constexpr int INTER_ = 1536;
constexpr int OUT_C = 80;
constexpr int TMEL_ = 1024;
constexpr int HD_ = 384;     // H*DH
constexpr int QKV_N = 1152;  // 3*HD

// Up to 8 split-K slice output pointers (passed by value as kernarg).
struct F8 {
  float* p[8];
};

// XCD-aware chunked swizzle (T1): bijective when nwg%8==0; identity otherwise.
__device__ __forceinline__ int xcd_swizzle(int bid, int nwg) {
  if (nwg & 7) return bid;
  return (bid & 7) * (nwg >> 3) + (bid >> 3);
}

// ===========================================================================
// Embedding + PE (PE indexed by BATCH per reference quirk): x = 2*emb + pe[b]
// Also computes the encoder key mask (fused).
// ===========================================================================
__global__ __launch_bounds__(256) void embed_kernel(
    const int* __restrict__ tokens, const float* __restrict__ emb,
    const int* __restrict__ tl, float* __restrict__ X, bf16* __restrict__ Xbf,
    float* __restrict__ maske) {
  int i = blockIdx.x * 256 + threadIdx.x;
  if (i >= B_ * T_ * D_) return;
  if (i < B_ * T_) {
    int bb = i / T_, tt = i % T_;
    maske[i] = (tt > tl[bb]) ? -INFINITY : 0.0f;
  }
  int d = i % D_;
  int bt = i / D_;
  int b = bt / T_, t = bt % T_;
  int tok = tokens[bt];
  int i2 = d & ~1;
  const float c = 9.210340371976184f / (float)D_;  // ln(10000)/D
  float freq = expf(-(float)i2 * c);
  float ang = (float)b * freq;
  float pe = (d & 1) ? cosf(ang) : sinf(ang);
  float v = 2.0f * emb[(size_t)tok * D_ + d] + pe;
  X[i] = v;
  Xbf[((size_t)b * (T_ + 2) + 1 + t) * D_ + d] = (bf16)v;
}

// ===========================================================================
// Weight transpose: src fp32 [K][N] -> dst bf16 [Ndst + rowOfs][K] row-major.
// ===========================================================================
__global__ __launch_bounds__(256) void transpose_w_kernel(
    const float* __restrict__ src, long srcLS, bf16* __restrict__ dst,
    long dstLS, int K, int N, int rowOfs) {
  src += (size_t)blockIdx.z * srcLS;
  dst += (size_t)blockIdx.z * dstLS;
  __shared__ float tile[32][33];
  const int tx = threadIdx.x & 31, ty = threadIdx.x >> 5;
  const int n0 = blockIdx.x * 32, k0 = blockIdx.y * 32;
#pragma unroll
  for (int j = 0; j < 4; ++j)
    tile[ty + j * 8][tx] =
        (n0 + tx < N) ? src[(size_t)(k0 + ty + j * 8) * N + n0 + tx] : 0.0f;
  __syncthreads();
#pragma unroll
  for (int j = 0; j < 4; ++j)
    dst[(size_t)(n0 + rowOfs + ty + j * 8) * K + k0 + tx] = (bf16)tile[tx][ty + j * 8];
}

// Zero padding rows of the three padded bf16 activation buffers in one launch.
__global__ void zero_pads3_kernel(bf16* a, bf16* c, bf16* m, int Tp) {
  int b = blockIdx.x >> 1, side = blockIdx.x & 1;
  size_t row = (size_t)b * (Tp + 2) + (side ? (Tp + 1) : 0);
  bf16* buf = (blockIdx.y == 0) ? a : (blockIdx.y == 1) ? c : m;
  int C = (blockIdx.y == 2) ? INTER_ : D_;
  for (int cc = threadIdx.x; cc < C; cc += 256) buf[row * C + cc] = (bf16)0.0f;
}

// ===========================================================================
// 128x128 GEMM (BK=32, 3-buf counted pipeline) — r14 structure (verified
// fastest; 4-buf/1-barrier variant regressed, r15; 4th decoder split-K slice
// raced with the combiner's bf16 writes, r16 — reverted to nz=3).
// Split-K slices via sp.p[z] (bias on z==0; relu only used when nz==1).
// nact: gap-tile skip (tiles [0,nact) + last tile kept).
// VTout: fused V-transpose; haloC: fused conv halo (rows act & 895).
// ===========================================================================
template <int TP>
__global__ __launch_bounds__(256) void mfma_gemm_kernel(
    const bf16* __restrict__ A, int lda, int aofs,
    const bf16* __restrict__ WT, int ldw, int kslice,
    const float* __restrict__ bias, int relu, F8 sp,
    bf16* __restrict__ Cbf, int ldc, int transC,
    const int* __restrict__ nact, bf16* __restrict__ VTout, int haloC) {
  __shared__ bf16 As[3][128 * 32];
  __shared__ bf16 Bs[3][128 * 32];
  const int tid = threadIdx.x;
  const int lane = tid & 63;
  const int wave = tid >> 6;
  const int wr = wave >> 1, wc = wave & 1;

  const int nT = gridDim.x, mT = gridDim.y;
  const int nwg = nT * mT * gridDim.z;
  int bid = blockIdx.x + nT * (blockIdx.y + mT * blockIdx.z);
  int wid = xcd_swizzle(bid, nwg);
  const int bx = wid % nT;
  int tmp = wid / nT;
  const int by = tmp % mT;
  const int z = tmp / mT;

  const int rowBase = by * 128;
  const int colBase = bx * 128;
  const int k0beg = z * kslice;
  const int nt = kslice / 32;
  const int bb = rowBase / TP;
  constexpr int LASTT = TP / 128 - 1;
  if (nact) {
    int tloc = (rowBase - bb * TP) >> 7;
    if (tloc >= nact[bb] && tloc != LASTT) return;  // gap-tile skip
  }
  const long pr0 = (long)bb * (TP + 2) + 1 + (rowBase - bb * TP);
  const long abase = pr0 * (long)lda - aofs;

  const int srow = tid >> 2, scb = tid & 3;

  auto stage = [&](int t, int buf) {  // 4 VMEM instructions per thread
    const int k0 = k0beg + t * 32;
#pragma unroll
    for (int e = 0; e < 2; ++e) {
      int idx = e * 256 + tid;
      int lrow = srow + e * 64;
      const bf16* gp = A + abase + (long)lrow * lda + k0 + ((scb ^ ((lrow >> 1) & 3)) << 3);
      __builtin_amdgcn_global_load_lds(
          (const __attribute__((address_space(1))) unsigned int*)gp,
          (__attribute__((address_space(3))) unsigned int*)(As[buf] + idx * 8), 16, 0, 0);
    }
#pragma unroll
    for (int e = 0; e < 2; ++e) {
      int idx = e * 256 + tid;
      int lrow = srow + e * 64;
      const bf16* gp = WT + (long)(colBase + lrow) * ldw + k0 + ((scb ^ ((lrow >> 1) & 3)) << 3);
      __builtin_amdgcn_global_load_lds(
          (const __attribute__((address_space(1))) unsigned int*)gp,
          (__attribute__((address_space(3))) unsigned int*)(Bs[buf] + idx * 8), 16, 0, 0);
    }
  };

  f32x4 acc[4][4] = {};
  const int g = lane >> 4, l15 = lane & 15;

  stage(0, 0);
  if (nt > 1) stage(1, 1);
  int cur = 0;
  for (int t = 0; t < nt; ++t) {
    if (t + 2 < nt) {
      int sb = cur + 2;
      if (sb >= 3) sb -= 3;
      stage(t + 2, sb);
    }
    int ahead = nt - 1 - t;
    if (ahead >= 2)
      asm volatile("s_waitcnt vmcnt(8)" ::: "memory");
    else if (ahead == 1)
      asm volatile("s_waitcnt vmcnt(4)" ::: "memory");
    else
      asm volatile("s_waitcnt vmcnt(0)" ::: "memory");
    __builtin_amdgcn_s_barrier();
    asm volatile("" ::: "memory");

    const bf16* Asb = As[cur];
    const bf16* Bsb = Bs[cur];
    bf16x8 af[4], bw[4];
#pragma unroll
    for (int m = 0; m < 4; ++m) {
      int row = wr * 64 + m * 16 + l15;
      int cb = g ^ ((row >> 1) & 3);
      af[m] = *(const bf16x8*)(Asb + row * 32 + cb * 8);
    }
#pragma unroll
    for (int n = 0; n < 4; ++n) {
      int row = wc * 64 + n * 16 + l15;
      int cb = g ^ ((row >> 1) & 3);
      bw[n] = *(const bf16x8*)(Bsb + row * 32 + cb * 8);
    }
#pragma unroll
    for (int m = 0; m < 4; ++m)
#pragma unroll
      for (int n = 0; n < 4; ++n)
        acc[m][n] = __builtin_amdgcn_mfma_f32_16x16x32_bf16(af[m], bw[n], acc[m][n], 0, 0, 0);

    asm volatile("" ::: "memory");
    __builtin_amdgcn_s_barrier();
    cur = (cur + 1 == 3) ? 0 : cur + 1;
  }

  float* Cfz = sp.p[z];
  const float* biasz = z ? nullptr : bias;
  const int qr = (lane >> 4) * 4;
  const int qc = lane & 15;
  const int actR = (haloC && nact) ? nact[bb] * 128 : -1;
#pragma unroll
  for (int m = 0; m < 4; ++m) {
    int lrow = wr * 64 + m * 16 + qr;
    int tl0 = rowBase - bb * TP + lrow;
#pragma unroll
    for (int n = 0; n < 4; ++n) {
      int gcol = colBase + wc * 64 + n * 16 + qc;
      float bv = (biasz && (!transC || gcol < OUT_C)) ? biasz[gcol] : 0.0f;
      float vq[4];
#pragma unroll
      for (int q = 0; q < 4; ++q) {
        float v = acc[m][n][q] + bv;
        if (relu) v = fmaxf(v, 0.0f);
        vq[q] = v;
      }
      if (transC) {
        if (gcol < OUT_C)
#pragma unroll
          for (int q = 0; q < 4; ++q)
            Cfz[((long)bb * OUT_C + gcol) * TMEL_ + tl0 + q] = vq[q];
      } else {
        if (Cfz)
#pragma unroll
          for (int q = 0; q < 4; ++q)
            Cfz[(long)(rowBase + lrow + q) * ldc + gcol] = vq[q];
        if (Cbf) {
#pragma unroll
          for (int q = 0; q < 4; ++q)
            Cbf[(pr0 + lrow + q) * ldc + gcol] = (bf16)vq[q];
          if (actR >= 0 && actR < 896) {
#pragma unroll
            for (int q = 0; q < 4; ++q)
              if (tl0 + q == actR - 1) {
                long pb = (long)bb * (TP + 2) + 1;
                bf16 hv = (bf16)vq[q];
                Cbf[(pb + actR) * (long)ldc + gcol] = hv;
                Cbf[(pb + 895) * (long)ldc + gcol] = hv;
              }
          }
        }
        if (VTout && gcol >= 768) {
          int hh = (gcol - 768) >> 6, dh = (gcol - 768) & 63;
          bf16x4 pk;
#pragma unroll
          for (int q = 0; q < 4; ++q) pk[q] = (bf16)vq[q];
          *(bf16x4*)(VTout + (((size_t)(bb * H_ + hh) * DH_ + dh) * TP + tl0)) = pk;
        }
      }
    }
  }
}

// ===========================================================================
// MFMA flash attention: key-tile skip + q-tile gap skip (last tile kept).
// ===========================================================================
__global__ __launch_bounds__(256) void attn4_kernel(
    const bf16* __restrict__ QKV, const bf16* __restrict__ VT,
    const float* __restrict__ maskadd, const int* __restrict__ lens,
    const int* __restrict__ nactp, bf16* __restrict__ Obf, int T) {
  const int nQT = gridDim.x;
  const int nwg = nQT * H_ * B_;
  int bid = blockIdx.x + nQT * (blockIdx.y + H_ * blockIdx.z);
  int wid = xcd_swizzle(bid, nwg);
  const int qt = wid % nQT;
  int tmp = wid / nQT;
  const int h = tmp % H_;
  const int b = tmp / H_;
  if (nactp) {
    int tloc = qt >> 1;  // 128-row tile index
    if (tloc >= nactp[b] && tloc != ((T >> 7) - 1)) return;
  }

  const int tid = threadIdx.x;
  const int lane = tid & 63;
  const int wave = tid >> 6;
  const int l15 = lane & 15, g = lane >> 4;

  __shared__ bf16 Ks[64 * 64];
  __shared__ bf16 Vts[64 * 64];
  __shared__ bf16 Ps[4][16 * 64];
  __shared__ float mask_s[TMEL_];

  const int q0 = qt * 64;
  const size_t brow0 = (size_t)b * (T + 2) + 1;

  for (int i = tid; i < T; i += 256) mask_s[i] = maskadd[(size_t)b * T + i];

  const size_t qrow = brow0 + q0 + wave * 16 + l15;
  bf16x8 qf0 = *(const bf16x8*)(QKV + qrow * QKV_N + h * DH_ + g * 8);
  bf16x8 qf1 = *(const bf16x8*)(QKV + qrow * QKV_N + h * DH_ + g * 8 + 32);

  float mreg[4], lreg[4];
#pragma unroll
  for (int r = 0; r < 4; ++r) { mreg[r] = -INFINITY; lreg[r] = 0.0f; }
  f32x4 oacc[4] = {};
  bf16* Psb = Ps[wave];

  const int nt = min(T >> 6, (lens[b] + 64) >> 6);
  for (int t = 0; t < nt; ++t) {
    const int k0 = t * 64;
#pragma unroll
    for (int it = 0; it < 2; ++it) {
      int c = it * 256 + tid;
      int r = c >> 3, d0 = c & 7;
      bf16x8 kv = *(const bf16x8*)(QKV + (brow0 + k0 + r) * QKV_N + 384 + h * DH_ + d0 * 8);
      *(bf16x8*)(Ks + r * 64 + ((d0 ^ (r & 7)) << 3)) = kv;
      bf16x8 vv = *(const bf16x8*)(VT + ((size_t)(b * H_ + h) * DH_ + r) * T + k0 + d0 * 8);
      *(bf16x8*)(Vts + r * 64 + ((d0 ^ (r & 7)) << 3)) = vv;
    }
    __syncthreads();

    f32x4 sacc[4] = {};
#pragma unroll
    for (int ks = 0; ks < 2; ++ks) {
#pragma unroll
      for (int n = 0; n < 4; ++n) {
        int key = n * 16 + l15;
        bf16x8 bf = *(const bf16x8*)(Ks + key * 64 + (((g + ks * 4) ^ (key & 7)) << 3));
        sacc[n] = __builtin_amdgcn_mfma_f32_16x16x32_bf16(ks ? qf1 : qf0, bf, sacc[n], 0, 0, 0);
      }
    }

    float s[4][4];
    float tm[4] = {-INFINITY, -INFINITY, -INFINITY, -INFINITY};
#pragma unroll
    for (int n = 0; n < 4; ++n) {
      float mv = mask_s[k0 + n * 16 + l15];
#pragma unroll
      for (int r = 0; r < 4; ++r) {
        float v = sacc[n][r] * 0.125f + mv;
        s[n][r] = v;
        tm[r] = fmaxf(tm[r], v);
      }
    }
#pragma unroll
    for (int msk = 1; msk < 16; msk <<= 1)
#pragma unroll
      for (int r = 0; r < 4; ++r) tm[r] = fmaxf(tm[r], __shfl_xor(tm[r], msk));

    float sc[4];
#pragma unroll
    for (int r = 0; r < 4; ++r) {
      float mn = fmaxf(mreg[r], tm[r]);
      sc[r] = __expf(mreg[r] - mn);
      mreg[r] = mn;
    }
    float psum[4] = {0.0f, 0.0f, 0.0f, 0.0f};
#pragma unroll
    for (int n = 0; n < 4; ++n) {
      int key = n * 16 + l15;
      int kblk = key >> 3, kin = key & 7;
#pragma unroll
      for (int r = 0; r < 4; ++r) {
        float p = __expf(s[n][r] - mreg[r]);
        psum[r] += p;
        int q = g * 4 + r;
        Psb[q * 64 + ((kblk ^ (q & 7)) << 3) + kin] = (bf16)p;
      }
    }
#pragma unroll
    for (int msk = 1; msk < 16; msk <<= 1)
#pragma unroll
      for (int r = 0; r < 4; ++r) psum[r] += __shfl_xor(psum[r], msk);
#pragma unroll
    for (int r = 0; r < 4; ++r) lreg[r] = lreg[r] * sc[r] + psum[r];
#pragma unroll
    for (int n = 0; n < 4; ++n)
#pragma unroll
      for (int r = 0; r < 4; ++r) oacc[n][r] *= sc[r];

#pragma unroll
    for (int ks = 0; ks < 2; ++ks) {
      bf16x8 af = *(const bf16x8*)(Psb + l15 * 64 + (((g + ks * 4) ^ (l15 & 7)) << 3));
#pragma unroll
      for (int n = 0; n < 4; ++n) {
        int dh = n * 16 + l15;
        bf16x8 bv = *(const bf16x8*)(Vts + dh * 64 + (((g + ks * 4) ^ (dh & 7)) << 3));
        oacc[n] = __builtin_amdgcn_mfma_f32_16x16x32_bf16(af, bv, oacc[n], 0, 0, 0);
      }
    }
    __syncthreads();
  }

  float inv[4];
#pragma unroll
  for (int r = 0; r < 4; ++r) inv[r] = 1.0f / lreg[r];
  const size_t orow = brow0 + q0 + wave * 16 + g * 4;
#pragma unroll
  for (int n = 0; n < 4; ++n)
#pragma unroll
    for (int r = 0; r < 4; ++r)
      Obf[(orow + r) * D_ + h * DH_ + n * 16 + l15] = (bf16)(oacc[n][r] * inv[r]);
}

// ===========================================================================
// Y = LN(opt-relu(X + sum_{i<nsl} sp.p[i])) * g + b. float4-vectorized.
// X nullable. Gap-tile skip (last tile kept); halo rows act & 895.
// ===========================================================================
__global__ __launch_bounds__(128) void add_ln_kernel(
    const float* __restrict__ X, F8 sp, int nsl,
    const float* __restrict__ g, const float* __restrict__ bb,
    float* __restrict__ Yf, bf16* __restrict__ Ybf, int tshift, int relu,
    const int* __restrict__ nactp, int halo) {
  const int row = blockIdx.x;
  const int b = row >> tshift, t = row & ((1 << tshift) - 1);
  if (nactp) {
    int tloc = t >> 7;
    if (tloc >= nactp[b] && tloc != (((1 << tshift) >> 7) - 1)) return;
  }
  const int tid = threadIdx.x;
  const bool lact = tid < 96;
  __shared__ float red[128];
  float4 v = make_float4(0.f, 0.f, 0.f, 0.f);
  if (lact) {
    if (X) v = ((const float4*)(X + (size_t)row * D_))[tid];
    for (int s = 0; s < nsl; ++s) {
      float4 h = ((const float4*)(sp.p[s] + (size_t)row * D_))[tid];
      v.x += h.x; v.y += h.y; v.z += h.z; v.w += h.w;
    }
    if (relu) {
      v.x = fmaxf(v.x, 0.f); v.y = fmaxf(v.y, 0.f);
      v.z = fmaxf(v.z, 0.f); v.w = fmaxf(v.w, 0.f);
    }
  }
  red[tid] = v.x + v.y + v.z + v.w;
  __syncthreads();
  for (int off = 64; off > 0; off >>= 1) {
    if (tid < off) red[tid] += red[tid + off];
    __syncthreads();
  }
  float mean = red[0] / (float)D_;
  __syncthreads();
  float dx = v.x - mean, dy = v.y - mean, dz = v.z - mean, dw = v.w - mean;
  red[tid] = lact ? (dx * dx + dy * dy + dz * dz + dw * dw) : 0.0f;
  __syncthreads();
  for (int off = 64; off > 0; off >>= 1) {
    if (tid < off) red[tid] += red[tid + off];
    __syncthreads();
  }
  float invstd = rsqrtf(red[0] / (float)D_ + 1e-5f);
  __syncthreads();
  if (!lact) return;
  float4 gv = ((const float4*)g)[tid];
  float4 bv = ((const float4*)bb)[tid];
  float4 y;
  y.x = dx * invstd * gv.x + bv.x;
  y.y = dy * invstd * gv.y + bv.y;
  y.z = dz * invstd * gv.z + bv.z;
  y.w = dw * invstd * gv.w + bv.w;
  ((float4*)(Yf + (size_t)row * D_))[tid] = y;
  if (Ybf) {
    const size_t pbase = (size_t)b * ((1 << tshift) + 2) + 1;
    bf16x4 p;
    p[0] = (bf16)y.x; p[1] = (bf16)y.y; p[2] = (bf16)y.z; p[3] = (bf16)y.w;
    *(bf16x4*)(Ybf + (pbase + t) * D_ + tid * 4) = p;
    if (halo && nactp) {
      int act = nactp[b] * 128;
      if (act < 896 && t == act - 1) {
        *(bf16x4*)(Ybf + (pbase + act) * D_ + tid * 4) = p;
        *(bf16x4*)(Ybf + (pbase + 895) * D_ + tid * 4) = p;
      }
    }
  }
}

__global__ __launch_bounds__(64) void dp_linear_kernel(
    const float* __restrict__ Hh, const float* __restrict__ w,
    const float* __restrict__ b0, float* __restrict__ lp) {
  const int row = blockIdx.x;
  const int tid = threadIdx.x;
  float s = 0.0f;
  for (int d = tid; d < D_; d += 64) s += Hh[(size_t)row * D_ + d] * w[d];
#pragma unroll
  for (int off = 32; off > 0; off >>= 1) s += __shfl_down(s, off);
  if (tid == 0) lp[row] = s + b0[0];
}

// ---------------------------------------------------------------------------
// Length regulator (fused scan + build; cumsum in LDS).
// ---------------------------------------------------------------------------
__global__ __launch_bounds__(256) void lr_prep_kernel(
    const int* __restrict__ dur, int* __restrict__ mel, int* __restrict__ nact,
    int* __restrict__ idx, float* __restrict__ maskd) {
  int b = blockIdx.x;
  __shared__ int cs_s[T_];
  __shared__ int smel;
  if (threadIdx.x == 0) {
    int s = 0;
    for (int t = 0; t < T_; ++t) {
      s += dur[b * T_ + t];
      cs_s[t] = s;
    }
    smel = s;
    mel[b] = s;
    nact[b] = (min(TMEL_, s + 9) + 127) >> 7;
  }
  __syncthreads();
  int mlen = smel;
  for (int m = threadIdx.x; m < TMEL_; m += 256) {
    int t = -1;
    if (m < mlen) {
      int lo = 0, hi = T_ - 1;
      while (lo < hi) {
        int mid = (lo + hi) >> 1;
        if (cs_s[mid] > m) hi = mid; else lo = mid + 1;
      }
      t = lo;
    }
    idx[b * TMEL_ + m] = t;
    maskd[b * TMEL_ + m] = (m > mlen) ? -INFINITY : 0.0f;
  }
}

__global__ __launch_bounds__(128) void lr_gather_kernel(
    const float* __restrict__ XE, const int* __restrict__ idx,
    float* __restrict__ XD, bf16* __restrict__ XDbf) {
  int row = blockIdx.x;
  int b = row / TMEL_, m = row % TMEL_;
  int t = idx[row];
  size_t prow = ((size_t)b * (TMEL_ + 2) + 1 + m) * D_;
  for (int d = threadIdx.x; d < D_; d += 128) {
    float v = (t >= 0) ? XE[((size_t)(b * T_ + t)) * D_ + d] : 0.0f;
    XD[(size_t)row * D_ + d] = v;
    XDbf[prow + d] = (bf16)v;
  }
}

// Broadcast gap mel columns [act*128, 896) from class column act*128-1.
__global__ void bcast_out_kernel(float* __restrict__ out,
                                 const int* __restrict__ nact) {
  int b = blockIdx.x / OUT_C, o = blockIdx.x % OUT_C;
  int act = nact[b] * 128;
  if (act >= 896) return;
  float* row = out + ((size_t)b * OUT_C + o) * TMEL_;
  float v = row[act - 1];
  for (int m = act + threadIdx.x; m < 896; m += 256) row[m] = v;
}

// ===========================================================================
// Host
// ===========================================================================
extern "C" void kernel_launch(void* const* d_in, const int* in_sizes, int n_in,
                              void* d_out, int out_size, void* d_ws, size_t ws_size,
                              hipStream_t stream) {
  const int* tokens = (const int*)d_in[0];
  const int* token_lengths = (const int*)d_in[1];
  const int* durations = (const int*)d_in[2];
  const float* emb = (const float*)d_in[3];
  const float* encw[12];
  const float* decw[12];
  for (int i = 0; i < 12; ++i) encw[i] = (const float*)d_in[4 + i];
  for (int i = 0; i < 12; ++i) decw[i] = (const float*)d_in[16 + i];
  const float* dp_c1w = (const float*)d_in[28];
  const float* dp_c1b = (const float*)d_in[29];
  const float* dp_ln1g = (const float*)d_in[30];
  const float* dp_ln1b = (const float*)d_in[31];
  const float* dp_c2w = (const float*)d_in[32];
  const float* dp_c2b = (const float*)d_in[33];
  const float* dp_ln2g = (const float*)d_in[34];
  const float* dp_ln2b = (const float*)d_in[35];
  const float* dp_w = (const float*)d_in[36];
  const float* dp_b = (const float*)d_in[37];
  const float* out_w = (const float*)d_in[38];
  const float* out_b = (const float*)d_in[39];

  float* out0 = (float*)d_out;                        // [B, OUT, TMEL]
  float* out_lp = out0 + (size_t)B_ * OUT_C * TMEL_;  // [B, T]

  // ---- workspace ----
  char* wsB = (char*)d_ws;
  size_t off = 0;
  auto alloc = [&](size_t bytes) {
    void* p = wsB + off;
    off = (off + bytes + 255) & ~(size_t)255;
    return p;
  };
  float* XE = (float*)alloc((size_t)B_ * T_ * D_ * 4);
  float* XD = (float*)alloc((size_t)B_ * TMEL_ * D_ * 4);
  float* YT = (float*)alloc((size_t)B_ * TMEL_ * D_ * 4);
  bf16* XEbf = (bf16*)alloc((size_t)B_ * (T_ + 2) * D_ * 2);
  bf16* XDbf = (bf16*)alloc((size_t)B_ * (TMEL_ + 2) * D_ * 2);
  bf16* YTbf = (bf16*)alloc((size_t)B_ * (TMEL_ + 2) * D_ * 2);
  bf16* MIDbf = (bf16*)alloc((size_t)B_ * (TMEL_ + 2) * INTER_ * 2);
  bf16* QKVbf = (bf16*)alloc((size_t)B_ * (TMEL_ + 2) * QKV_N * 2);
  bf16* OBbf = (bf16*)alloc((size_t)B_ * (TMEL_ + 2) * D_ * 2);   // 6.30 MB
  bf16* VTb = (bf16*)alloc((size_t)B_ * H_ * DH_ * TMEL_ * 2);    // 6.29 MB, adjacent
  float* OF = (float*)QKVbf;  // fp32 slice 0 (aliases QKVbf; disjoint lifetime)
  float* PT2 = (float*)OBbf;  // conv2 slice 1: OBbf+VTb contiguous span (both dead)
  float* YTal = (float*)YT;   // WO slice 1: YT dead there; add_ln reads first
  float* XDal = (float*)XD;   // dec conv2 slice 2: XD dead during conv2; combiner
                              // reads row r before rewriting row r (row-local safe)
  float* EARENA = (float*)((char*)MIDbf + (8u << 20));  // enc conv2 slices (MIDbf tail)
  float* DARENA = (float*)MIDbf;                        // DP slices (MIDbf dead)
  const size_t ESS = (size_t)B_ * T_ * D_;  // per-slice elems

  bf16* QKVT = (bf16*)alloc((size_t)L_ * QKV_N * D_ * 2);
  bf16* WOT = (bf16*)alloc((size_t)L_ * D_ * D_ * 2);
  bf16* C1T = (bf16*)alloc((size_t)L_ * INTER_ * (3 * D_) * 2);
  bf16* C2T = (bf16*)alloc((size_t)L_ * D_ * (3 * INTER_) * 2);
  bf16* DP1T = (bf16*)alloc((size_t)D_ * (3 * D_) * 2);
  bf16* DP2T = (bf16*)alloc((size_t)D_ * (3 * D_) * 2);
  bf16* OUTT = (bf16*)alloc((size_t)128 * D_ * 2);
  float* MASKE = (float*)alloc(B_ * T_ * 4);
  float* MASKD = (float*)alloc(B_ * TMEL_ * 4);
  int* MEL = (int*)alloc(B_ * 4);
  int* NACT = (int*)alloc(B_ * 4);
  int* IDX = (int*)alloc(B_ * TMEL_ * 4);

  auto tw = [&](const float* s, long sls, bf16* d, long dls, int K, int N,
                int Ndst, int ro, int Lz) {
    transpose_w_kernel<<<dim3(Ndst / 32, K / 32, Lz), 256, 0, stream>>>(s, sls, d, dls, K, N, ro);
  };
  auto gemm = [&](int TP, int nT, int mT, int nz, const bf16* A, int lda, int aofs,
                  const bf16* WTp, int ldw, int kslice, const float* bias, int relu,
                  F8 sp, bf16* Cbf, int ldc, int transC,
                  const int* nact, bf16* VTout, int haloC) {
    dim3 gd(nT, mT, nz);
    if (TP == 128)
      mfma_gemm_kernel<128><<<gd, 256, 0, stream>>>(A, lda, aofs, WTp, ldw, kslice,
                                                    bias, relu, sp, Cbf, ldc, transC,
                                                    nact, VTout, haloC);
    else
      mfma_gemm_kernel<1024><<<gd, 256, 0, stream>>>(A, lda, aofs, WTp, ldw, kslice,
                                                     bias, relu, sp, Cbf, ldc, transC,
                                                     nact, VTout, haloC);
  };

  F8 spNull = {};
  auto run_layer = [&](int TP, const float* const* w, int i, float* Xf, bf16* Xbf,
                       const float* mask, const int* lens, const int* nact) {
    const int mT = B_ * TP / 128;
    const int tshift = (TP == 128) ? 7 : 10;
    // QKV GEMM with fused V-transpose
    gemm(TP, QKV_N / 128, mT, 1, Xbf, D_, 0, QKVT + (size_t)i * QKV_N * D_, D_, D_,
         nullptr, 0, spNull, QKVbf, QKV_N, 0, nact, VTb, 0);
    attn4_kernel<<<dim3(TP / 64, H_, B_), 256, 0, stream>>>(QKVbf, VTb, mask, lens, nact, OBbf, TP);
    // WO split-K=2
    F8 spWO = {};
    spWO.p[0] = OF; spWO.p[1] = YTal;
    gemm(TP, D_ / 128, mT, 2, OBbf, D_, 0, WOT + (size_t)i * D_ * D_, D_, D_ / 2,
         nullptr, 0, spWO, nullptr, D_, 0, nact, nullptr, 0);
    add_ln_kernel<<<B_ * TP, 128, 0, stream>>>(Xf, spWO, 2, w[4] + (size_t)i * D_,
                                               w[5] + (size_t)i * D_, YT, YTbf, tshift, 0,
                                               nact, 1);  // halo: YTbf rows act & 895
    // conv1 (nz=1, relu+bf16+halo in epilogue)
    gemm(TP, INTER_ / 128, mT, 1, YTbf, D_, D_, C1T + (size_t)i * INTER_ * 3 * D_, 3 * D_,
         3 * D_, w[7] + (size_t)i * INTER_, 1, spNull, MIDbf, INTER_, 0,
         nact, nullptr, 1);
    // conv2 split-K: encoder nz=8 (arena), decoder nz=3 (OF, PT2, XD)
    F8 spC2 = {};
    int nzC2;
    if (TP == 128) {
      nzC2 = 8;
      for (int s = 0; s < 8; ++s) spC2.p[s] = EARENA + (size_t)s * ESS;
    } else {
      nzC2 = 3;
      spC2.p[0] = OF; spC2.p[1] = PT2; spC2.p[2] = XDal;
    }
    gemm(TP, D_ / 128, mT, nzC2, MIDbf, INTER_, INTER_, C2T + (size_t)i * D_ * 3 * INTER_,
         3 * INTER_, 3 * INTER_ / nzC2, w[9] + (size_t)i * D_, 0, spC2, nullptr, D_, 0,
         nact, nullptr, 0);
    add_ln_kernel<<<B_ * TP, 128, 0, stream>>>(YT, spC2, nzC2, w[10] + (size_t)i * D_,
                                               w[11] + (size_t)i * D_, Xf, Xbf, tshift, 0,
                                               nact, 0);
  };

  // 1) embed + enc mask (fused) + pad zeroing
  embed_kernel<<<(B_ * T_ * D_ + 255) / 256, 256, 0, stream>>>(tokens, emb, token_lengths,
                                                               XE, XEbf, MASKE);
  zero_pads3_kernel<<<dim3(B_ * 2, 3), 256, 0, stream>>>(XEbf, YTbf, MIDbf, T_);

  // 2) encoder weights (batched) + stack
  tw(encw[0], (long)D_ * HD_, QKVT, (long)QKV_N * D_, D_, HD_, HD_, 0, L_);
  tw(encw[1], (long)D_ * HD_, QKVT, (long)QKV_N * D_, D_, HD_, HD_, 384, L_);
  tw(encw[2], (long)D_ * HD_, QKVT, (long)QKV_N * D_, D_, HD_, HD_, 768, L_);
  tw(encw[3], (long)HD_ * D_, WOT, (long)D_ * D_, HD_, D_, D_, 0, L_);
  tw(encw[6], (long)3 * D_ * INTER_, C1T, (long)INTER_ * 3 * D_, 3 * D_, INTER_, INTER_, 0, L_);
  tw(encw[8], (long)3 * INTER_ * D_, C2T, (long)D_ * 3 * INTER_, 3 * INTER_, D_, D_, 0, L_);
  for (int i = 0; i < L_; ++i)
    run_layer(T_, encw, i, XE, XEbf, MASKE, token_lengths, nullptr);

  // 3) duration predictor (split-K=4 via DP arena; relu in add_ln)
  tw(dp_c1w, 0, DP1T, 0, 3 * D_, D_, D_, 0, 1);
  tw(dp_c2w, 0, DP2T, 0, 3 * D_, D_, D_, 0, 1);
  F8 spDP = {};
  for (int s = 0; s < 4; ++s) spDP.p[s] = DARENA + (size_t)s * ESS;
  F8 spDPs = {};
  for (int s = 0; s < 3; ++s) spDPs.p[s] = DARENA + (size_t)(s + 1) * ESS;
  gemm(128, D_ / 128, B_, 4, XEbf, D_, D_, DP1T, 3 * D_, 3 * D_ / 4, dp_c1b, 0,
       spDP, nullptr, D_, 0, nullptr, nullptr, 0);
  add_ln_kernel<<<B_ * T_, 128, 0, stream>>>(spDP.p[0], spDPs, 3, dp_ln1g, dp_ln1b,
                                             YT, YTbf, 7, 1, nullptr, 0);
  gemm(128, D_ / 128, B_, 4, YTbf, D_, D_, DP2T, 3 * D_, 3 * D_ / 4, dp_c2b, 0,
       spDP, nullptr, D_, 0, nullptr, nullptr, 0);
  add_ln_kernel<<<B_ * T_, 128, 0, stream>>>(spDP.p[0], spDPs, 3, dp_ln2g, dp_ln2b,
                                             YT, nullptr, 7, 1, nullptr, 0);
  dp_linear_kernel<<<B_ * T_, 64, 0, stream>>>(YT, dp_w, dp_b, out_lp);

  // 4) length regulator
  lr_prep_kernel<<<B_, 256, 0, stream>>>(durations, MEL, NACT, IDX, MASKD);
  zero_pads3_kernel<<<dim3(B_ * 2, 3), 256, 0, stream>>>(XDbf, YTbf, MIDbf, TMEL_);
  lr_gather_kernel<<<B_ * TMEL_, 128, 0, stream>>>(XE, IDX, XD, XDbf);

  // 5) decoder weights (batched) + stack (gap-tile skip via NACT)
  tw(decw[0], (long)D_ * HD_, QKVT, (long)QKV_N * D_, D_, HD_, HD_, 0, L_);
  tw(decw[1], (long)D_ * HD_, QKVT, (long)QKV_N * D_, D_, HD_, HD_, 384, L_);
  tw(decw[2], (long)D_ * HD_, QKVT, (long)QKV_N * D_, D_, HD_, HD_, 768, L_);
  tw(decw[3], (long)HD_ * D_, WOT, (long)D_ * D_, HD_, D_, D_, 0, L_);
  tw(decw[6], (long)3 * D_ * INTER_, C1T, (long)INTER_ * 3 * D_, 3 * D_, INTER_, INTER_, 0, L_);
  tw(decw[8], (long)3 * INTER_ * D_, C2T, (long)D_ * 3 * INTER_, 3 * INTER_, D_, D_, 0, L_);
  for (int i = 0; i < L_; ++i)
    run_layer(TMEL_, decw, i, XD, XDbf, MASKD, MEL, NACT);

  // 6) final projection (gap skip, last tile computed) + gap column broadcast
  tw(out_w, 0, OUTT, 0, D_, OUT_C, 128, 0, 1);
  F8 spOut = {};
  spOut.p[0] = out0;
  gemm(1024, 1, B_ * TMEL_ / 128, 1, XDbf, D_, 0, OUTT, D_, D_, out_b, 0,
       spOut, nullptr, 0, 1, NACT, nullptr, 0);
  bcast_out_kernel<<<B_ * OUT_C, 256, 0, stream>>>(out0, NACT);
}